// Round 2
// baseline (2129.327 us; speedup 1.0000x reference)
//
#include <hip/hip_runtime.h>

#define BT_ 32768
#define DM 1024
#define DH 4096
#define NE 16
#define CAP 2560

using u64 = unsigned long long;
typedef __attribute__((ext_vector_type(8))) short short8;
typedef __attribute__((ext_vector_type(4))) float f32x4;

__device__ __forceinline__ unsigned short f2b(float f) {
  unsigned int i = __float_as_uint(f);
  unsigned int r = (i + 0x7FFFu + ((i >> 16) & 1u)) >> 16;  // RNE
  return (unsigned short)r;
}
__device__ __forceinline__ float b2f(unsigned short u) {
  return __uint_as_float(((unsigned int)u) << 16);
}
__device__ __forceinline__ float gelu_tanh(float v) {
  // jax.nn.gelu default: tanh approximation
  float u = 0.7978845608028654f * (v + 0.044715f * v * v * v);
  float t = 1.0f - 2.0f / (__expf(2.0f * u) + 1.0f);
  return 0.5f * v * (1.0f + t);
}

// ---------------- gating (fp32 exact) + x -> bf16 conversion ----------------
__global__ __launch_bounds__(256) void k_gate(const float* __restrict__ x,
                                              const float* __restrict__ gw,
                                              unsigned short* __restrict__ xb,
                                              float* __restrict__ scores,
                                              int* __restrict__ eids) {
  int wave = threadIdx.x >> 6, lane = threadIdx.x & 63;
  int t = blockIdx.x * 4 + wave;
  const float4* xr = (const float4*)(x + (size_t)t * DM + lane * 16);
  float xv[16];
#pragma unroll
  for (int q = 0; q < 4; q++) {
    float4 v = xr[q];
    xv[q * 4 + 0] = v.x; xv[q * 4 + 1] = v.y; xv[q * 4 + 2] = v.z; xv[q * 4 + 3] = v.w;
  }
  // write bf16 copy of x (32B per lane, coalesced)
  uint4 pk[2];
#pragma unroll
  for (int h = 0; h < 2; h++) {
    unsigned int w[4];
#pragma unroll
    for (int q = 0; q < 4; q++)
      w[q] = (unsigned int)f2b(xv[h * 8 + q * 2]) | ((unsigned int)f2b(xv[h * 8 + q * 2 + 1]) << 16);
    pk[h].x = w[0]; pk[h].y = w[1]; pk[h].z = w[2]; pk[h].w = w[3];
  }
  uint4* xo = (uint4*)(xb + (size_t)t * DM + lane * 16);
  xo[0] = pk[0]; xo[1] = pk[1];

  float lg[NE];
#pragma unroll
  for (int e = 0; e < NE; e++) {
    const float4* gr = (const float4*)(gw + e * DM + lane * 16);
    float p = 0.f;
#pragma unroll
    for (int q = 0; q < 4; q++) {
      float4 v = gr[q];
      p += xv[q * 4 + 0] * v.x + xv[q * 4 + 1] * v.y + xv[q * 4 + 2] * v.z + xv[q * 4 + 3] * v.w;
    }
#pragma unroll
    for (int s = 32; s > 0; s >>= 1) p += __shfl_down(p, s, 64);
    lg[e] = p;
  }
  if (lane == 0) {
    float m = lg[0]; int ei = 0;
#pragma unroll
    for (int e = 1; e < NE; e++) if (lg[e] > m) { m = lg[e]; ei = e; }  // ties -> lowest idx
    float s = 0.f;
#pragma unroll
    for (int e = 0; e < NE; e++) s += expf(lg[e] - m);
    scores[t] = 1.0f / s;   // top1 softmax prob
    eids[t] = ei;
  }
}

// ---------------- per-expert token list ----------------
__global__ __launch_bounds__(256) void k_compact(const int* __restrict__ eids,
                                                 int* __restrict__ cnt,
                                                 int* __restrict__ lists) {
  int t = blockIdx.x * 256 + threadIdx.x;
  int e = eids[t];
  int p = atomicAdd(&cnt[e], 1);
  lists[e * BT_ + p] = t;
}

// ---------------- exact top-C selection (64b key bisection) ----------------
__global__ __launch_bounds__(256) void k_select(const int* __restrict__ cnt,
                                                const int* __restrict__ lists,
                                                const float* __restrict__ scores,
                                                int* __restrict__ sel) {
  int e = blockIdx.x, tid = threadIdx.x;
  int n = cnt[e];
  const int* lst = lists + e * BT_;
  int* se = sel + e * CAP;
  if (n <= CAP) {
    for (int i = tid; i < CAP; i += 256) se[i] = (i < n) ? lst[i] : -1;
    return;
  }
  __shared__ u64 s_lo, s_hi;
  __shared__ int s_red[256];
  __shared__ int s_pos;
  if (tid == 0) { s_lo = 0ull; s_hi = ~0ull; s_pos = 0; }
  __syncthreads();
  for (;;) {
    u64 lo = s_lo, hi = s_hi;
    if (hi - lo <= 1) break;
    u64 mid = lo + ((hi - lo) >> 1);
    int c = 0;
    for (int i = tid; i < n; i += 256) {
      int t = lst[i];
      u64 key = (((u64)__float_as_uint(scores[t])) << 32) | (u64)(~(unsigned)t);
      c += (key >= mid) ? 1 : 0;
    }
    s_red[tid] = c; __syncthreads();
    for (int s = 128; s > 0; s >>= 1) {
      if (tid < s) s_red[tid] += s_red[tid + s];
      __syncthreads();
    }
    if (tid == 0) { if (s_red[0] >= CAP) s_lo = mid; else s_hi = mid; }
    __syncthreads();
  }
  u64 thr = s_lo;
  for (int i = tid; i < n; i += 256) {
    int t = lst[i];
    u64 key = (((u64)__float_as_uint(scores[t])) << 32) | (u64)(~(unsigned)t);
    if (key >= thr) { int p = atomicAdd(&s_pos, 1); se[p] = t; }
  }
}

// ---------- [R,C] fp32 -> [C,R] bf16 transpose+convert per expert ----------
__global__ __launch_bounds__(256) void k_transcvt(const float* __restrict__ in,
                                                  unsigned short* __restrict__ out,
                                                  int R, int Cc) {
  __shared__ unsigned short tile[64][66];
  int e = blockIdx.z;
  const float* ip = in + (size_t)e * R * Cc;
  unsigned short* op = out + (size_t)e * R * Cc;
  int r0 = blockIdx.y * 64, c0 = blockIdx.x * 64;
  int rr = threadIdx.x >> 4;
  int cc = (threadIdx.x & 15) * 4;
#pragma unroll
  for (int p = 0; p < 4; p++) {
    int r = rr + p * 16;
    float4 v = *(const float4*)(ip + (size_t)(r0 + r) * Cc + c0 + cc);
    tile[cc + 0][r] = f2b(v.x); tile[cc + 1][r] = f2b(v.y);
    tile[cc + 2][r] = f2b(v.z); tile[cc + 3][r] = f2b(v.w);
  }
  __syncthreads();
#pragma unroll
  for (int p = 0; p < 4; p++) {
    int r = rr + p * 16;
    ushort4 v;
    v.x = tile[r][cc]; v.y = tile[r][cc + 1]; v.z = tile[r][cc + 2]; v.w = tile[r][cc + 3];
    *(ushort4*)(op + (size_t)(c0 + r) * R + r0 + cc) = v;
  }
}

// ---------------- m97-style bt GEMM, 128x128 tile, BK=32, bf16 MFMA --------
// MODE 0: A rows gathered via sel (xb rows), epilogue bias+gelu -> bf16 Hbuf
// MODE 1: A dense (Hbuf), epilogue bias -> fp32 scatter rows into y via sel
template <int MODE>
__global__ __launch_bounds__(256) void k_gemm(const unsigned short* __restrict__ A,
                                              const unsigned short* __restrict__ Bt,
                                              const float* __restrict__ bias,
                                              unsigned short* __restrict__ OutB,
                                              float* __restrict__ OutF,
                                              const int* __restrict__ sel,
                                              int M, int N, int K) {
  __shared__ __align__(128) unsigned short As[128 * 32];
  __shared__ __align__(128) unsigned short Bs[128 * 32];
  int e = blockIdx.z;
  int mBase = blockIdx.y * 128, nBase = blockIdx.x * 128;
  int tid = threadIdx.x, wave = tid >> 6, lane = tid & 63;
  int quad = lane >> 4, l16 = lane & 15;
  int wm = (wave & 1) * 64, wn = (wave >> 1) * 64;

  // staging geometry: tile row = 32 bf16 = 64 B; wave w stages rows [32w, 32w+32)
  int o1 = wave * 2048 + lane * 16;   // byte offset in 8 KB tile
  int o2 = o1 + 1024;
  int r1 = o1 >> 6, c1 = (o1 & 63) >> 1;  // c in ushorts
  int r2 = o2 >> 6, c2 = (o2 & 63) >> 1;
  const unsigned short *gA1, *gA2;
  if (MODE == 0) {
    int t1 = sel[e * CAP + mBase + r1]; if (t1 < 0) t1 = 0;
    int t2 = sel[e * CAP + mBase + r2]; if (t2 < 0) t2 = 0;
    gA1 = A + (size_t)t1 * K + c1;
    gA2 = A + (size_t)t2 * K + c2;
  } else {
    gA1 = A + ((size_t)e * M + mBase + r1) * K + c1;
    gA2 = A + ((size_t)e * M + mBase + r2) * K + c2;
  }
  const unsigned short* gB1 = Bt + ((size_t)e * N + nBase + r1) * K + c1;
  const unsigned short* gB2 = Bt + ((size_t)e * N + nBase + r2) * K + c2;
  unsigned short* lA = As + wave * 1024;  // = wave*2048 bytes
  unsigned short* lB = Bs + wave * 1024;

  f32x4 acc[4][4] = {};

  for (int k0 = 0; k0 < K; k0 += 32) {
    __builtin_amdgcn_global_load_lds((const __attribute__((address_space(1))) void*)(gA1 + k0),
                                     (__attribute__((address_space(3))) void*)lA, 16, 0, 0);
    __builtin_amdgcn_global_load_lds((const __attribute__((address_space(1))) void*)(gA2 + k0),
                                     (__attribute__((address_space(3))) void*)(lA + 512), 16, 0, 0);
    __builtin_amdgcn_global_load_lds((const __attribute__((address_space(1))) void*)(gB1 + k0),
                                     (__attribute__((address_space(3))) void*)lB, 16, 0, 0);
    __builtin_amdgcn_global_load_lds((const __attribute__((address_space(1))) void*)(gB2 + k0),
                                     (__attribute__((address_space(3))) void*)(lB + 512), 16, 0, 0);
    __syncthreads();
    short8 af[4], bf[4];
#pragma unroll
    for (int i = 0; i < 4; i++)
      af[i] = *(const short8*)(As + (wm + i * 16 + l16) * 32 + quad * 8);
#pragma unroll
    for (int j = 0; j < 4; j++)
      bf[j] = *(const short8*)(Bs + (wn + j * 16 + l16) * 32 + quad * 8);
#pragma unroll
    for (int i = 0; i < 4; i++)
#pragma unroll
      for (int j = 0; j < 4; j++)
        acc[i][j] = __builtin_amdgcn_mfma_f32_16x16x32_bf16(af[i], bf[j], acc[i][j], 0, 0, 0);
    __syncthreads();
  }

#pragma unroll
  for (int i = 0; i < 4; i++) {
#pragma unroll
    for (int r = 0; r < 4; r++) {
      int gm = mBase + wm + i * 16 + quad * 4 + r;
      int tok = 0;
      size_t orow;
      if (MODE == 0) {
        orow = ((size_t)e * M + gm) * (size_t)N;
      } else {
        tok = sel[e * CAP + gm];
        orow = (size_t)(tok < 0 ? 0 : tok) * (size_t)N;
      }
#pragma unroll
      for (int j = 0; j < 4; j++) {
        int gn = nBase + wn + j * 16 + l16;
        float v = acc[i][j][r] + bias[e * N + gn];
        if (MODE == 0) {
          OutB[orow + gn] = f2b(gelu_tanh(v));
        } else if (tok >= 0) {
          OutF[orow + gn] = v;
        }
      }
    }
  }
}

// ---------------- lb_loss & overflow ----------------
__global__ void k_loss(const int* __restrict__ cnt, float* __restrict__ out2) {
  if (threadIdx.x == 0 && blockIdx.x == 0) {
    float lb = 0.f, ov = 0.f;
    for (int e = 0; e < NE; e++) {
      float c = (float)cnt[e];
      float d = c - 2048.0f;
      lb += d * d;
      float x = c - (float)CAP;
      if (x > 0.f) ov += x;
    }
    lb = (lb / 16.0f) / (2048.0f * 2048.0f);
    ov = ov / 32768.0f;
    out2[0] = lb;
    out2[1] = ov;
  }
}

extern "C" void kernel_launch(void* const* d_in, const int* in_sizes, int n_in,
                              void* d_out, int out_size, void* d_ws, size_t ws_size,
                              hipStream_t stream) {
  const float* x  = (const float*)d_in[0];
  const float* gw = (const float*)d_in[1];
  const float* w1 = (const float*)d_in[2];
  const float* b1 = (const float*)d_in[3];
  const float* w2 = (const float*)d_in[4];
  const float* b2 = (const float*)d_in[5];
  float* out = (float*)d_out;

  char* ws = (char*)d_ws;
  size_t off = 0;
  auto alloc = [&](size_t bytes) -> void* {
    void* p = ws + off;
    off = (off + bytes + 255) & ~(size_t)255;
    return p;
  };
  float* scores        = (float*)alloc((size_t)BT_ * 4);
  int* eids            = (int*)alloc((size_t)BT_ * 4);
  int* cnt             = (int*)alloc(64);
  int* lists           = (int*)alloc((size_t)NE * BT_ * 4);
  int* sel             = (int*)alloc((size_t)NE * CAP * 4);
  unsigned short* xb   = (unsigned short*)alloc((size_t)BT_ * DM * 2);      // [BT][D] bf16
  unsigned short* w1t  = (unsigned short*)alloc((size_t)NE * DH * DM * 2);  // [E][H][D] bf16
  unsigned short* w2t  = (unsigned short*)alloc((size_t)NE * DM * DH * 2);  // [E][D][H] bf16
  unsigned short* Hbuf = (unsigned short*)alloc((size_t)NE * CAP * DH * 2); // [E][C][H] bf16

  hipMemsetAsync(cnt, 0, 64, stream);
  // y initialized to x (covers any dropped tokens; GEMM2 overwrites routed rows)
  hipMemcpyAsync(out, x, (size_t)BT_ * DM * 4, hipMemcpyDeviceToDevice, stream);

  k_gate<<<BT_ / 4, 256, 0, stream>>>(x, gw, xb, scores, eids);
  k_compact<<<BT_ / 256, 256, 0, stream>>>(eids, cnt, lists);
  k_select<<<NE, 256, 0, stream>>>(cnt, lists, scores, sel);
  k_transcvt<<<dim3(DH / 64, DM / 64, NE), 256, 0, stream>>>(w1, w1t, DM, DH);
  k_transcvt<<<dim3(DM / 64, DH / 64, NE), 256, 0, stream>>>(w2, w2t, DH, DM);
  k_gemm<0><<<dim3(DH / 128, CAP / 128, NE), 256, 0, stream>>>(xb, w1t, b1, Hbuf, nullptr, sel, CAP, DH, DM);
  k_gemm<1><<<dim3(DM / 128, CAP / 128, NE), 256, 0, stream>>>(Hbuf, w2t, b2, nullptr, out, sel, CAP, DM, DH);
  k_loss<<<1, 64, 0, stream>>>(cnt, out + (size_t)BT_ * DM);
}